// Round 1
// baseline (13513.913 us; speedup 1.0000x reference)
//
#include <hip/hip_runtime.h>
#include <hip/hip_bf16.h>

typedef __attribute__((ext_vector_type(8))) __bf16 bf16x8;
typedef __attribute__((ext_vector_type(4))) __bf16 bf16x4;
typedef __attribute__((ext_vector_type(4))) float  f32x4;

#define L_LEN   8192
#define D_DIM   2048
#define G_NUM   256
#define HP      8320     // per-copy length of Hrev8 (elems), incl. 64-front/64-back zero pad
#define HS      680      // LDS per-copy stride (elems) -> 340 dwords, %32=20: copies spread over banks
#define KVS     136      // LDS kv row stride (elems) -> 68 dwords, %32=4

// ---- pass 1: kv = x2*v, transpose (b,l,d) -> [g][c=b*8+dg][l], cast bf16 ----
__global__ __launch_bounds__(256) void prep_kv_kernel(
    const float* __restrict__ x2, const float* __restrict__ v,
    __bf16* __restrict__ kvout)
{
  __shared__ __bf16 sT[64 * 66];  // [d_local][l_local], stride 66 (33 dw, %32=1: conflict-lite)
  const int tid = threadIdx.x;
  const int l0 = blockIdx.x << 6;
  const int d0 = blockIdx.y << 6;
  const int b  = blockIdx.z;
  const int col = tid & 63, r4 = tid >> 6;
#pragma unroll
  for (int rr = 0; rr < 16; ++rr) {
    const int lloc = (rr << 2) + r4;
    const size_t idx = ((size_t)(b * L_LEN + l0 + lloc)) * D_DIM + d0 + col;
    sT[col * 66 + lloc] = (__bf16)(x2[idx] * v[idx]);
  }
  __syncthreads();
  const int ch = tid >> 2, seg = tid & 3;
  const int gch = d0 + ch;
  const int row = ((gch >> 3) << 4) + (b << 3) + (gch & 7);  // g*16 + b*8 + dg
  bf16x8 a0, a1;
#pragma unroll
  for (int k = 0; k < 8; ++k) {
    a0[k] = sT[ch * 66 + (seg << 4) + k];
    a1[k] = sT[ch * 66 + (seg << 4) + 8 + k];
  }
  __bf16* dst = kvout + (size_t)row * L_LEN + l0 + (seg << 4);
  *(bf16x8*)dst = a0;
  *(bf16x8*)(dst + 8) = a1;
}

// ---- pass 2: Hrev8[g][s][z] = Hrev(z - 64 + s), Hrev(x) = h[g][8191 - x] (0 outside) ----
__global__ __launch_bounds__(256) void prep_h_kernel(
    const float* __restrict__ h, __bf16* __restrict__ hr)
{
  const unsigned i = blockIdx.x * 256u + threadIdx.x;  // exact: grid*256 == 256*8*HP
  const unsigned g = i / (8u * HP);
  const unsigned r = i - g * (8u * HP);
  const unsigned s = r / HP;
  const unsigned z = r - s * HP;
  const int P = 8255 - (int)z - (int)s;  // = 8191 - (z - 64 + s)
  __bf16 val = (__bf16)0.0f;
  if (P >= 0 && P < 8192) val = (__bf16)h[(size_t)g * 8192 + P];
  hr[i] = val;
}

// ---- pass 3: Toeplitz MFMA conv + bias + x1 gating + transpose-out ----
// block: one group g, 512 l; 4 waves x 8 M-tiles(16 l); N=16 channels; K super-iter = 128 taps
__global__ __launch_bounds__(256, 2) void conv_kernel(
    const __bf16* __restrict__ KV, const __bf16* __restrict__ HR,
    const float* __restrict__ x1, const float* __restrict__ bias,
    float* __restrict__ out)
{
  __shared__ __bf16 sKV[16 * KVS];
  __shared__ __bf16 sH[8 * HS];

  const int g   = blockIdx.x;
  const int jb  = 15 - (int)blockIdx.y;  // heavy l-blocks first
  const int l0  = jb << 9;
  const int tid = threadIdx.x;
  const int lane = tid & 63, wv = tid >> 6;
  const int m = lane & 15, q = lane >> 4;

  const __bf16* __restrict__ KVg = KV + (size_t)g * (16 * L_LEN);
  const __bf16* __restrict__ HRg = HR + (size_t)g * (8 * HP);

  f32x4 acc[8];
#pragma unroll
  for (int i = 0; i < 8; ++i)
#pragma unroll
    for (int r = 0; r < 4; ++r) acc[i][r] = 0.0f;

  bf16x8 zed;
#pragma unroll
  for (int k = 0; k < 8; ++k) zed[k] = (__bf16)0.0f;

  const int cst = tid >> 4, tst = (tid & 15) << 3;  // kv staging: row, 8-elem chunk
  const int s_c   = (7 - m) & 7;                    // lane's shift-copy (constant: all offsets %8==0)
  const int bbase = m * KVS + (q << 3);             // B-frag: n = lane&15, k-block = q

  const int send = l0 + 512;
  for (int tb = 0; tb < send; tb += 128) {
    __syncthreads();
    // stage kv[g][c][tb..tb+128)
    *(bf16x8*)&sKV[cst * KVS + tst] = *(const bf16x8*)&KVg[cst * L_LEN + tb + tst];
    // stage h window: 8 copies x 656 elems
    const int Bv = 8255 - l0 + tb;          // = XC + 64 - l0 + tb
    const int Y0 = (Bv - 518) & ~7;
    for (int u = tid; u < 8 * 82; u += 256) {
      const int s   = u / 82;
      const int off = (u - s * 82) << 3;
      const int yy  = Y0 + off;
      bf16x8 w = zed;
      if (yy + 8 <= HP) w = *(const bf16x8*)&HRg[s * HP + yy];
      *(bf16x8*)&sH[s * HS + off] = w;
    }
    __syncthreads();

    const int zbase = Bv - (wv << 7) - m + (q << 3);
    const int abase = s_c * HS + (zbase - s_c - Y0) - 112;  // frag idx d'+7 -> abase + 16*idx
    const int thr   = l0 + (wv << 7) + 16 - tb;  // MFMA(i,jj) valid iff 32*jj < thr + 16*i
    bf16x8 af[14];  // Toeplitz dedup: frag depends only on d' = 2*jj - i  (idx = d'+7)
#pragma unroll
    for (int jj = 0; jj < 4; ++jj) {
      const bf16x8 bfrag = *(const bf16x8*)&sKV[bbase + (jj << 5)];
      if (jj == 0) {
#pragma unroll
        for (int idx = 0; idx < 8; ++idx)
          af[idx] = *(const bf16x8*)&sH[abase + (idx << 4)];
      } else {
        af[6 + (jj << 1)] = *(const bf16x8*)&sH[abase + ((6 + (jj << 1)) << 4)];
        af[7 + (jj << 1)] = *(const bf16x8*)&sH[abase + ((7 + (jj << 1)) << 4)];
      }
#pragma unroll
      for (int i = 0; i < 8; ++i) {
        if ((jj << 5) < thr + (i << 4))
          acc[i] = __builtin_amdgcn_mfma_f32_16x16x32_bf16(
              af[7 + (jj << 1) - i], bfrag, acc[i], 0, 0, 0);
      }
    }
  }

  // epilogue: y += kv*bias; out = x1 * y, scattered back to (b,l,d)
  const int c = m;
  const int bb = c >> 3, dg = c & 7;
  const float bv = bias[(g << 3) + dg];
#pragma unroll
  for (int i = 0; i < 8; ++i) {
    const int l = l0 + (wv << 7) + (i << 4) + (q << 2);  // C/D row = q*4 + r
    const bf16x4 kv4 = *(const bf16x4*)&KVg[c * L_LEN + l];
#pragma unroll
    for (int r = 0; r < 4; ++r) {
      const float y = acc[i][r] + (float)kv4[r] * bv;
      const size_t oidx = ((size_t)(bb * L_LEN + l + r)) * D_DIM + (g << 3) + dg;
      out[oidx] = x1[oidx] * y;
    }
  }
}

extern "C" void kernel_launch(void* const* d_in, const int* in_sizes, int n_in,
                              void* d_out, int out_size, void* d_ws, size_t ws_size,
                              hipStream_t stream)
{
  const float* x1 = (const float*)d_in[0];
  const float* x2 = (const float*)d_in[1];
  const float* v  = (const float*)d_in[2];
  const float* h  = (const float*)d_in[3];
  const float* cb = (const float*)d_in[4];
  float* out = (float*)d_out;

  // workspace: kv bf16 [256][16][8192] = 64 MiB, then Hrev8 bf16 [256][8][8320] = 32.5 MiB
  __bf16* kv = (__bf16*)d_ws;
  __bf16* hr = kv + (size_t)G_NUM * 16 * L_LEN;

  prep_kv_kernel<<<dim3(L_LEN / 64, D_DIM / 64, 2), 256, 0, stream>>>(x2, v, kv);
  prep_h_kernel<<<(G_NUM * 8 * HP) / 256, 256, 0, stream>>>(h, hr);
  conv_kernel<<<dim3(G_NUM, 16), 256, 0, stream>>>(kv, hr, x1, cb, out);
}

// Round 2
// 835.596 us; speedup vs baseline: 16.1728x; 16.1728x over previous
//
#include <hip/hip_runtime.h>
#include <hip/hip_bf16.h>

typedef __attribute__((ext_vector_type(8))) __bf16 bf16x8;
typedef __attribute__((ext_vector_type(4))) __bf16 bf16x4;
typedef __attribute__((ext_vector_type(4))) float  f32x4;

#define L_LEN   8192
#define D_DIM   2048
#define G_NUM   256
#define HP      8320     // per-copy length of Hrev8 (elems), incl. 64-front/64-back zero pad
#define HS      680      // LDS per-copy stride (elems) -> 340 dwords, %32=20
#define KVS     136      // LDS kv row stride (elems) -> 68 dwords, %32=4

// ---- pass 1: kv = x2*v, transpose (b,l,d) -> [g][c=b*8+dg][l], cast bf16 ----
__global__ __launch_bounds__(256) void prep_kv_kernel(
    const float* __restrict__ x2, const float* __restrict__ v,
    __bf16* __restrict__ kvout)
{
  __shared__ __bf16 sT[64 * 66];
  const int tid = threadIdx.x;
  const int l0 = blockIdx.x << 6;
  const int d0 = blockIdx.y << 6;
  const int b  = blockIdx.z;
  const int col = tid & 63, r4 = tid >> 6;
#pragma unroll
  for (int rr = 0; rr < 16; ++rr) {
    const int lloc = (rr << 2) + r4;
    const size_t idx = ((size_t)(b * L_LEN + l0 + lloc)) * D_DIM + d0 + col;
    sT[col * 66 + lloc] = (__bf16)(x2[idx] * v[idx]);
  }
  __syncthreads();
  const int ch = tid >> 2, seg = tid & 3;
  const int gch = d0 + ch;
  const int row = ((gch >> 3) << 4) + (b << 3) + (gch & 7);  // g*16 + b*8 + dg
  bf16x8 a0, a1;
#pragma unroll
  for (int k = 0; k < 8; ++k) {
    a0[k] = sT[ch * 66 + (seg << 4) + k];
    a1[k] = sT[ch * 66 + (seg << 4) + 8 + k];
  }
  __bf16* dst = kvout + (size_t)row * L_LEN + l0 + (seg << 4);
  *(bf16x8*)dst = a0;
  *(bf16x8*)(dst + 8) = a1;
}

// ---- pass 2: Hrev8[g][s][z] = Hrev(z - 64 + s), Hrev(x) = h[g][8191 - x] (0 outside) ----
__global__ __launch_bounds__(256) void prep_h_kernel(
    const float* __restrict__ h, __bf16* __restrict__ hr)
{
  const unsigned i = blockIdx.x * 256u + threadIdx.x;
  const unsigned g = i / (8u * HP);
  const unsigned r = i - g * (8u * HP);
  const unsigned s = r / HP;
  const unsigned z = r - s * HP;
  const int P = 8255 - (int)z - (int)s;
  __bf16 val = (__bf16)0.0f;
  if (P >= 0 && P < 8192) val = (__bf16)h[(size_t)g * 8192 + P];
  hr[i] = val;
}

// ---- pass 3: Toeplitz MFMA conv + bias + x1 gating + transpose-out ----
// block: one group g, 512 l; 4 waves x 8 M-tiles(16 l); N=16 channels; K super-iter = 128 taps
// NOTE: no local arrays anywhere in this kernel (round-1 showed the compiler
// scratch-spilled af[]/acc[] state -> 46 GB of HBM write traffic). Named accs +
// immediate-use A-frag temps keep live state ~70 VGPRs.
__global__ __launch_bounds__(256, 4) void conv_kernel(
    const __bf16* __restrict__ KV, const __bf16* __restrict__ HR,
    const float* __restrict__ x1, const float* __restrict__ bias,
    float* __restrict__ out)
{
  __shared__ __bf16 sKV[16 * KVS];
  __shared__ __bf16 sH[8 * HS];

  const int g   = blockIdx.x;
  const int jb  = 15 - (int)blockIdx.y;  // heavy l-blocks first
  const int l0  = jb << 9;
  const int tid = threadIdx.x;
  const int lane = tid & 63, wv = tid >> 6;
  const int m = lane & 15, q = lane >> 4;

  const __bf16* __restrict__ KVg = KV + (size_t)g * (16 * L_LEN);
  const __bf16* __restrict__ HRg = HR + (size_t)g * (8 * HP);

  f32x4 acc0 = {0.f,0.f,0.f,0.f}, acc1 = acc0, acc2 = acc0, acc3 = acc0,
        acc4 = acc0, acc5 = acc0, acc6 = acc0, acc7 = acc0;

  bf16x8 zed;
#pragma unroll
  for (int k = 0; k < 8; ++k) zed[k] = (__bf16)0.0f;

  const int cst = tid >> 4, tst = (tid & 15) << 3;  // kv staging: row, 8-elem chunk
  const int s_c   = (7 - m) & 7;                    // lane's shift-copy
  const int bbase = m * KVS + (q << 3);             // B-frag: n = lane&15, k-block = q

  const int send = l0 + 512;
  for (int tb = 0; tb < send; tb += 128) {
    __syncthreads();
    // stage kv[g][c][tb..tb+128)
    *(bf16x8*)&sKV[cst * KVS + tst] = *(const bf16x8*)&KVg[cst * L_LEN + tb + tst];
    // stage h window: 8 copies x 656 elems
    const int Bv = 8255 - l0 + tb;
    const int Y0 = (Bv - 518) & ~7;
    for (int u = tid; u < 8 * 82; u += 256) {
      const int s   = u / 82;
      const int off = (u - s * 82) << 3;
      const int yy  = Y0 + off;
      bf16x8 w = zed;
      if (yy + 8 <= HP) w = *(const bf16x8*)&HRg[s * HP + yy];
      *(bf16x8*)&sH[s * HS + off] = w;
    }
    __syncthreads();

    const int zbase = Bv - (wv << 7) - m + (q << 3);
    const int abase = s_c * HS + (zbase - s_c - Y0) - 112;  // A-frag idx d'+7 -> abase + 16*idx
    const int thr   = l0 + (wv << 7) + 16 - tb;  // MFMA(i,jj) valid iff 32*jj < thr + 16*i

#define CONV_STEP(i, accv)                                                      \
    if ((jj << 5) < thr + ((i) << 4)) {                                         \
      const bf16x8 afr =                                                        \
          *(const bf16x8*)&sH[abase + ((7 + (jj << 1) - (i)) << 4)];            \
      accv = __builtin_amdgcn_mfma_f32_16x16x32_bf16(afr, bfrag, accv, 0, 0, 0);\
    }

#pragma unroll
    for (int jj = 0; jj < 4; ++jj) {
      const bf16x8 bfrag = *(const bf16x8*)&sKV[bbase + (jj << 5)];
      CONV_STEP(0, acc0)
      CONV_STEP(1, acc1)
      CONV_STEP(2, acc2)
      CONV_STEP(3, acc3)
      CONV_STEP(4, acc4)
      CONV_STEP(5, acc5)
      CONV_STEP(6, acc6)
      CONV_STEP(7, acc7)
    }
#undef CONV_STEP
  }

  // epilogue: y += kv*bias; out = x1 * y, scattered back to (b,l,d)
  const int c = m;
  const int bb = c >> 3, dg = c & 7;
  const float bv = bias[(g << 3) + dg];

#define CONV_EPI(i, accv) {                                                     \
    const int l = l0 + (wv << 7) + ((i) << 4) + (q << 2);                       \
    const bf16x4 kv4 = *(const bf16x4*)&KVg[c * L_LEN + l];                     \
    for (int r = 0; r < 4; ++r) {                                               \
      const float y = accv[r] + (float)kv4[r] * bv;                             \
      const size_t oidx = ((size_t)(bb * L_LEN + l + r)) * D_DIM + (g << 3) + dg;\
      out[oidx] = x1[oidx] * y;                                                 \
    } }

  CONV_EPI(0, acc0)
  CONV_EPI(1, acc1)
  CONV_EPI(2, acc2)
  CONV_EPI(3, acc3)
  CONV_EPI(4, acc4)
  CONV_EPI(5, acc5)
  CONV_EPI(6, acc6)
  CONV_EPI(7, acc7)
#undef CONV_EPI
}

extern "C" void kernel_launch(void* const* d_in, const int* in_sizes, int n_in,
                              void* d_out, int out_size, void* d_ws, size_t ws_size,
                              hipStream_t stream)
{
  const float* x1 = (const float*)d_in[0];
  const float* x2 = (const float*)d_in[1];
  const float* v  = (const float*)d_in[2];
  const float* h  = (const float*)d_in[3];
  const float* cb = (const float*)d_in[4];
  float* out = (float*)d_out;

  // workspace: kv bf16 [256][16][8192] = 64 MiB, then Hrev8 bf16 [256][8][8320] = 32.5 MiB
  __bf16* kv = (__bf16*)d_ws;
  __bf16* hr = kv + (size_t)G_NUM * 16 * L_LEN;

  prep_kv_kernel<<<dim3(L_LEN / 64, D_DIM / 64, 2), 256, 0, stream>>>(x2, v, kv);
  prep_h_kernel<<<(G_NUM * 8 * HP) / 256, 256, 0, stream>>>(h, hr);
  conv_kernel<<<dim3(G_NUM, 16), 256, 0, stream>>>(kv, hr, x1, cb, out);
}